// Round 22
// baseline (123.005 us; speedup 1.0000x reference)
//
#include <hip/hip_runtime.h>
#include <math.h>

typedef unsigned long long u64;
typedef unsigned short ushort_t;
typedef float f32x4 __attribute__((ext_vector_type(4)));
typedef short short8 __attribute__((ext_vector_type(8)));

#define BB 4
#define NN 2048
#define FINE 256
#define FOUTE 256
#define HH 4
#define DD 64
#define NW 32   // 2048/64 packed words per adj row
#define L2E 1.44269504088896340736f

#define EXP2F(x) __builtin_amdgcn_exp2f(x)   // v_exp_f32: 2^x
#define LOG2F(x) __builtin_amdgcn_logf(x)    // v_log_f32: log2(x)

__device__ __forceinline__ float lrelu(float x) { return fmaxf(x, 0.2f * x); }

__device__ __forceinline__ unsigned short f2bf(float x) {   // fp32 -> bf16 RNE
  unsigned u = __float_as_uint(x);
  unsigned r = u + 0x7FFFu + ((u >> 16) & 1u);
  return (unsigned short)(r >> 16);
}

__device__ __forceinline__ unsigned cvtpk(float lo, float hi) {  // 2xf32 -> packed bf16 pair, 1 op
  unsigned r;
  asm("v_cvt_pk_bf16_f32 %0, %1, %2" : "=v"(r) : "v"(lo), "v"(hi));
  return r;
}

// ---------------- K1: FUSED {projection GEMM (x<128)} | {adj pack + h_new zero (x>=128)} ----------------
// GEMM needs (BB*NN)/64 = 128 x-blocks (m0 = bx*64 < 8192). Pack covers rows ((bx-128)<<2)|y.
__global__ __launch_bounds__(256) void k_pg(const float* __restrict__ hI, const float* __restrict__ W,
                                            const float* __restrict__ attn,
                                            ushort_t* __restrict__ hpT,
                                            float* __restrict__ sB, float* __restrict__ tB,
                                            float* __restrict__ tB4,
                                            const int* __restrict__ adj, u64* __restrict__ pack,
                                            float4* __restrict__ outZero) {
  __shared__ ushort_t Ab[64 * 256];     // [m][k] bf16, byte ^= (m&7)<<4 within row
  __shared__ ushort_t Bb[64 * 256];     // [d][k] bf16, same swizzle
  __shared__ ushort_t tT[64][72];       // transposed bf16 tile [d][token]
  int bx = blockIdx.x;
  int tid = threadIdx.x;

  if (bx >= 128) {
    // ---------- pack branch: row = ((bx-128)<<2) | blockIdx.y ----------
    int row = ((bx - 128) << 2) | blockIdx.y;
    if (row < 2048) outZero[(size_t)row * 256 + tid] = make_float4(0.f, 0.f, 0.f, 0.f);
    int wv = tid >> 6, ln = tid & 63;
    const int* arow = adj + (size_t)row * NN;
    u64* prow = pack + (size_t)row * NW;
    for (int w = wv; w < NW; w += 4) {
      u64 m = __ballot(arow[(w << 6) + ln] != 0);
      if (ln == 0) prow[w] = m;
    }
    return;
  }

  // ---------- projection GEMM branch ----------
  int m0 = bx * 64;                     // over M = B*N (bx < 128 -> m0 < 8192)
  int hh = blockIdx.y;
  int f0 = hh * 64;
  int w = tid >> 6, lane = tid & 63;
  int li = lane & 15, g = lane >> 4;

#pragma unroll
  for (int q = 0; q < 16; ++q) {
    int fi = (q << 8) + tid;            // 0..4095 float4-chunks
    int row = fi >> 6, f4 = fi & 63;
    float4 va = *(const float4*)&hI[(size_t)(m0 + row) * FINE + (f4 << 2)];
    float4 vb = *(const float4*)&W[(size_t)(f0 + row) * FINE + (f4 << 2)];
    int byteOff = (row << 9) + ((f4 << 3) ^ ((row & 7) << 4));
    *(uint2*)((char*)Ab + byteOff) = make_uint2(cvtpk(va.x, va.y), cvtpk(va.z, va.w));
    *(uint2*)((char*)Bb + byteOff) = make_uint2(cvtpk(vb.x, vb.y), cvtpk(vb.z, vb.w));
  }
  __syncthreads();

  f32x4 acc[4] = {};
  int arow = (w << 4) + li;
  int abase = arow << 9, asw = (arow & 7) << 4;
#pragma unroll
  for (int kk = 0; kk < 8; ++kk) {
    short8 a = *(const short8*)((char*)Ab + abase + (((kk << 6) + (g << 4)) ^ asw));
#pragma unroll
    for (int f = 0; f < 4; ++f) {
      int brow = (f << 4) + li;
      short8 b = *(const short8*)((char*)Bb + (brow << 9) + (((kk << 6) + (g << 4)) ^ ((brow & 7) << 4)));
      acc[f] = __builtin_amdgcn_mfma_f32_16x16x32_bf16(a, b, acc[f], 0, 0, 0);
    }
  }

  // ---- fused s/t from acc, scaled by log2(e): downstream softmax runs in exp2/log2 domain ----
  float as4[4], ad4[4];
#pragma unroll
  for (int f = 0; f < 4; ++f) {
    as4[f] = attn[(hh << 7) + (f << 4) + li] * L2E;
    ad4[f] = attn[(hh << 7) + 64 + (f << 4) + li] * L2E;
  }
  float ps[4] = {0.f, 0.f, 0.f, 0.f}, pt[4] = {0.f, 0.f, 0.f, 0.f};
#pragma unroll
  for (int f = 0; f < 4; ++f)
#pragma unroll
    for (int r = 0; r < 4; ++r) { ps[r] += acc[f][r] * as4[f]; pt[r] += acc[f][r] * ad4[f]; }
#pragma unroll
  for (int off = 1; off <= 8; off <<= 1) {
#pragma unroll
    for (int r = 0; r < 4; ++r) { ps[r] += __shfl_xor(ps[r], off); pt[r] += __shfl_xor(pt[r], off); }
  }
  int b0 = m0 >> 11, n0 = m0 & (NN - 1);
  if (li == 0) {
#pragma unroll
    for (int r = 0; r < 4; ++r) {
      int nn = n0 + (w << 4) + (g << 2) + r;
      size_t idx = (size_t)(b0 * HH + hh) * NN + nn;
      sB[idx] = ps[r]; tB[idx] = pt[r];
      tB4[((size_t)b0 * NN + nn) * 4 + hh] = pt[r];
    }
  }
  // ---- transposed bf16 store via LDS ----
#pragma unroll
  for (int f = 0; f < 4; ++f)
#pragma unroll
    for (int r = 0; r < 4; ++r)
      tT[(f << 4) + li][(w << 4) + (g << 2) + r] = f2bf(acc[f][r]);
  __syncthreads();
#pragma unroll
  for (int q = 0; q < 2; ++q) {
    int dr = (q << 5) + (tid >> 3);
    int seg = tid & 7;
    *(short8*)&hpT[((size_t)((b0 * HH + hh) << 6) + dr) * NN + n0 + (seg << 3)] =
        *(const short8*)&tT[dr][seg << 3];
  }
}

// ---------------- K2: fused ml+mean (log2 domain), LDS-staged t4, 8 rows/block, 1024 blocks ----------------
__global__ __launch_bounds__(256) void k_mls(const float* __restrict__ sB, const float* __restrict__ tB4,
                                             const u64* __restrict__ pack, float* __restrict__ cB,
                                             float* __restrict__ outMean) {
  __shared__ float4 t4s[2048];          // 32 KB: whole t4 table of this b
  __shared__ float4 wpart[4];
  int tid = threadIdx.x;
  int lane = tid & 63;
  int wv = tid >> 6;
  int bbase = blockIdx.x << 3;          // 8 rows per block, never straddles b
  int b = bbase >> 11;
  const float4* t4 = (const float4*)tB4 + (size_t)b * NN;
#pragma unroll
  for (int q = 0; q < 8; ++q) t4s[(q << 8) + tid] = t4[(q << 8) + tid];
  __syncthreads();

  // ---- block-wide unmasked max of t per head (softmax shift-invariance) ----
  float4 pm = make_float4(-1e30f, -1e30f, -1e30f, -1e30f);
#pragma unroll
  for (int q = 0; q < 8; ++q) {
    float4 tv = t4s[(wv << 9) + (q << 6) + lane];
    pm.x = fmaxf(pm.x, tv.x); pm.y = fmaxf(pm.y, tv.y);
    pm.z = fmaxf(pm.z, tv.z); pm.w = fmaxf(pm.w, tv.w);
  }
#pragma unroll
  for (int off = 32; off; off >>= 1) {
    pm.x = fmaxf(pm.x, __shfl_xor(pm.x, off));
    pm.y = fmaxf(pm.y, __shfl_xor(pm.y, off));
    pm.z = fmaxf(pm.z, __shfl_xor(pm.z, off));
    pm.w = fmaxf(pm.w, __shfl_xor(pm.w, off));
  }
  if (lane == 0) wpart[wv] = pm;
  __syncthreads();
  float4 q0 = wpart[0], q1 = wpart[1], q2 = wpart[2], q3 = wpart[3];
  float tmax[4] = {fmaxf(fmaxf(q0.x, q1.x), fmaxf(q2.x, q3.x)),
                   fmaxf(fmaxf(q0.y, q1.y), fmaxf(q2.y, q3.y)),
                   fmaxf(fmaxf(q0.z, q1.z), fmaxf(q2.z, q3.z)),
                   fmaxf(fmaxf(q0.w, q1.w), fmaxf(q2.w, q3.w))};

  int r0 = __builtin_amdgcn_readfirstlane(bbase + (wv << 1));   // first of this wave's 2 rows
  const u64* p0 = pack + (size_t)(r0 + 0) * NW;
  const u64* p1 = pack + (size_t)(r0 + 1) * NW;
  float sv[2][4], Ah[2][4], Bh[2][4], mh[2][4];
#pragma unroll
  for (int r = 0; r < 2; ++r)
#pragma unroll
    for (int h = 0; h < 4; ++h) {
      float s = sB[(size_t)(b * HH + h) * NN + ((r0 + r) & (NN - 1))];
      float m = lrelu(s + tmax[h]);
      sv[r][h] = s; mh[r][h] = m; Ah[r][h] = s - m; Bh[r][h] = fmaf(0.2f, s, -m);
    }
  unsigned mr0 = 0, mr1 = 0;            // bit k = adj(row, 64k+lane)
  float4 ls0 = make_float4(0.f, 0.f, 0.f, 0.f), ls1 = ls0;
#pragma unroll 4
  for (int k = 0; k < NW; ++k) {
    bool b0 = (p0[k] >> lane) & 1ull, b1 = (p1[k] >> lane) & 1ull;
    mr0 |= (unsigned)b0 << k; mr1 |= (unsigned)b1 << k;
    float4 tv = t4s[(k << 6) + lane];
    ls0.x += b0 ? EXP2F(fmaxf(tv.x + Ah[0][0], fmaf(0.2f, tv.x, Bh[0][0]))) : 0.f;
    ls0.y += b0 ? EXP2F(fmaxf(tv.y + Ah[0][1], fmaf(0.2f, tv.y, Bh[0][1]))) : 0.f;
    ls0.z += b0 ? EXP2F(fmaxf(tv.z + Ah[0][2], fmaf(0.2f, tv.z, Bh[0][2]))) : 0.f;
    ls0.w += b0 ? EXP2F(fmaxf(tv.w + Ah[0][3], fmaf(0.2f, tv.w, Bh[0][3]))) : 0.f;
    ls1.x += b1 ? EXP2F(fmaxf(tv.x + Ah[1][0], fmaf(0.2f, tv.x, Bh[1][0]))) : 0.f;
    ls1.y += b1 ? EXP2F(fmaxf(tv.y + Ah[1][1], fmaf(0.2f, tv.y, Bh[1][1]))) : 0.f;
    ls1.z += b1 ? EXP2F(fmaxf(tv.z + Ah[1][2], fmaf(0.2f, tv.z, Bh[1][2]))) : 0.f;
    ls1.w += b1 ? EXP2F(fmaxf(tv.w + Ah[1][3], fmaf(0.2f, tv.w, Bh[1][3]))) : 0.f;
  }
#pragma unroll
  for (int off = 32; off; off >>= 1) {
    ls0.x += __shfl_xor(ls0.x, off); ls0.y += __shfl_xor(ls0.y, off);
    ls0.z += __shfl_xor(ls0.z, off); ls0.w += __shfl_xor(ls0.w, off);
    ls1.x += __shfl_xor(ls1.x, off); ls1.y += __shfl_xor(ls1.y, off);
    ls1.z += __shfl_xor(ls1.z, off); ls1.w += __shfl_xor(ls1.w, off);
  }
  float A2[2][4], B2[2][4];
  float lv0[4] = {ls0.x, ls0.y, ls0.z, ls0.w};
  float lv1[4] = {ls1.x, ls1.y, ls1.z, ls1.w};
#pragma unroll
  for (int h = 0; h < 4; ++h) {
    float c0 = mh[0][h] + LOG2F(lv0[h]);
    float c1 = mh[1][h] + LOG2F(lv1[h]);
    A2[0][h] = sv[0][h] - c0; B2[0][h] = fmaf(0.2f, sv[0][h], -c0);
    A2[1][h] = sv[1][h] - c1; B2[1][h] = fmaf(0.2f, sv[1][h], -c1);
    if (lane == 0) {
      cB[(size_t)(b * HH + h) * NN + ((r0 + 0) & (NN - 1))] = c0;
      cB[(size_t)(b * HH + h) * NN + ((r0 + 1) & (NN - 1))] = c1;
    }
  }
#pragma unroll 2
  for (int k = 0; k < NW; ++k) {
    float4 tv = t4s[(k << 6) + lane];
    float tvv[4] = {tv.x, tv.y, tv.z, tv.w};
    float a0 = 0.f, a1 = 0.f;
#pragma unroll
    for (int h = 0; h < 4; ++h) {
      a0 += EXP2F(fmaxf(tvv[h] + A2[0][h], fmaf(0.2f, tvv[h], B2[0][h])));
      a1 += EXP2F(fmaxf(tvv[h] + A2[1][h], fmaf(0.2f, tvv[h], B2[1][h])));
    }
    outMean[(size_t)(r0 + 0) * NN + (k << 6) + lane] = ((mr0 >> k) & 1u) ? 0.25f * a0 : 0.0f;
    outMean[(size_t)(r0 + 1) * NN + (k << 6) + lane] = ((mr1 >> k) & 1u) ? 0.25f * a1 : 0.0f;
  }
}

// ---------------- K3: h_new = alpha @ hp via bf16 MFMA; distance-2 pipeline, j-half split;
// block's 4 KB t-half staged ONCE in LDS ----------------
__global__ __launch_bounds__(256) void k_pv(const ushort_t* __restrict__ hpT,
                                            const float* __restrict__ sB, const float* __restrict__ cB,
                                            const float* __restrict__ tB, const u64* __restrict__ pack,
                                            float* __restrict__ out) {
  __shared__ ushort_t hpTile[2][4096];  // [buf][64 d-rows][64 j] bf16, XOR-swizzled (slot ^= drow&7)
  __shared__ float4 tLds[256];          // 4 KB: this block's j-half of t (float4 -> aligned)
  int blk = blockIdx.x;
  int jh = blockIdx.y;                  // j-half: jc in [16*jh, 16*jh+16)
  int it = blk & 31, bh = blk >> 5;
  int b = bh >> 2, hh = bh & 3;
  int i0 = it << 6;
  int tid = threadIdx.x;
  int w = tid >> 6, lane = tid & 63;
  int li = lane & 15, g = lane >> 4;
  int irow = i0 + (w << 4) + li;        // alpha row this lane generates
  float sI = sB[(size_t)bh * NN + irow];
  float cI = cB[(size_t)bh * NN + irow];
  float A0 = sI - cI, B0 = fmaf(0.2f, sI, -cI);   // exact: max(x,0.2x)-c == max(x-c, 0.2x-c)
  const u64* packRow = pack + ((size_t)b * NN + irow) * NW;
  const float* tRow = tB + (size_t)bh * NN;

  int drow0 = (w << 4) + (lane >> 3);           // q=0 rows; q=1 adds 8
  int xslot = (lane & 7) ^ (lane >> 3);         // (slot ^ drow&7); same for q=0/1
  const ushort_t* srcBase0 = hpT + ((size_t)(bh << 6) + drow0) * NN + (xslot << 3);
  const ushort_t* srcBase1 = srcBase0 + (size_t)8 * NN;

#define STAGE(buf, j0c)                                                                        \
  do {                                                                                         \
    __builtin_amdgcn_global_load_lds(                                                          \
        (const __attribute__((address_space(1))) void*)(srcBase0 + (j0c)),                     \
        (__attribute__((address_space(3))) void*)&hpTile[buf][(w << 10)], 16, 0, 0);           \
    __builtin_amdgcn_global_load_lds(                                                          \
        (const __attribute__((address_space(1))) void*)(srcBase1 + (j0c)),                     \
        (__attribute__((address_space(3))) void*)&hpTile[buf][(w << 10) + 512], 16, 0, 0);     \
  } while (0)

  f32x4 acc[4] = {};
  int jc0 = jh << 4;
  STAGE(0, jc0 << 6);
  STAGE(1, (jc0 + 1) << 6);
  // stage this j-half's t values once (1024 floats; each thread one float4)
  tLds[tid] = ((const float4*)(tRow + (jc0 << 6)))[tid];
  u64 wbits = packRow[jc0];             // vector load AFTER STAGEs: its vmcnt drain covers them
  __syncthreads();                      // tLds ready
  int cur = 0;

  for (int jc = jc0; jc < jc0 + 16; ++jc) {
    const float4* tq = tLds + ((jc - jc0) << 4) + (g << 1);
    float4 ta0 = tq[0], ta1 = tq[1], tb0 = tq[8], tb1 = tq[9];   // +32 floats = +8 float4
    float tva[8] = {ta0.x, ta0.y, ta0.z, ta0.w, ta1.x, ta1.y, ta1.z, ta1.w};
    float tvb[8] = {tb0.x, tb0.y, tb0.z, tb0.w, tb1.x, tb1.y, tb1.z, tb1.w};
    unsigned bits0 = (unsigned)(wbits >> (g << 3));
    unsigned bits1 = (unsigned)(wbits >> (32 + (g << 3)));
    float ea[8], eb[8];
#pragma unroll
    for (int jj = 0; jj < 8; ++jj) {
      float e0 = EXP2F(fmaxf(tva[jj] + A0, fmaf(0.2f, tva[jj], B0)));
      ea[jj] = ((bits0 >> jj) & 1u) ? e0 : 0.0f;
      float e1 = EXP2F(fmaxf(tvb[jj] + A0, fmaf(0.2f, tvb[jj], B0)));
      eb[jj] = ((bits1 >> jj) & 1u) ? e1 : 0.0f;
    }
    uint4 ua, ub;
    ua.x = cvtpk(ea[0], ea[1]); ua.y = cvtpk(ea[2], ea[3]);
    ua.z = cvtpk(ea[4], ea[5]); ua.w = cvtpk(ea[6], ea[7]);
    ub.x = cvtpk(eb[0], eb[1]); ub.y = cvtpk(eb[2], eb[3]);
    ub.z = cvtpk(eb[4], eb[5]); ub.w = cvtpk(eb[6], eb[7]);
    short8 a0 = __builtin_bit_cast(short8, ua);
    short8 a1 = __builtin_bit_cast(short8, ub);

    if (jc < jc0 + 15) wbits = packRow[jc + 1];   // preload mask for jc+1 under MFMA phase

    asm volatile("" ::: "memory");
    __builtin_amdgcn_sched_barrier(0);
    __builtin_amdgcn_s_barrier();
    __builtin_amdgcn_sched_barrier(0);

    const char* tile = (const char*)hpTile[cur];
#pragma unroll
    for (int f = 0; f < 4; ++f) {
      int dr = (f << 4) + li;
      int ro = dr << 7;
      int sw = (dr & 7) << 4;
      short8 b0 = *(const short8*)(tile + ro + ((g << 4) ^ sw));
      short8 b1 = *(const short8*)(tile + ro + ((64 + (g << 4)) ^ sw));
      acc[f] = __builtin_amdgcn_mfma_f32_16x16x32_bf16(a0, b0, acc[f], 0, 0, 0);
      acc[f] = __builtin_amdgcn_mfma_f32_16x16x32_bf16(a1, b1, acc[f], 0, 0, 0);
    }

    asm volatile("s_waitcnt lgkmcnt(0)" ::: "memory");
    __builtin_amdgcn_sched_barrier(0);
    __builtin_amdgcn_s_barrier();

    if (jc + 2 < jc0 + 16) STAGE(cur, (jc + 2) << 6);
    cur ^= 1;
  }
#undef STAGE

#pragma unroll
  for (int f = 0; f < 4; ++f)
#pragma unroll
    for (int r = 0; r < 4; ++r) {
      int i = i0 + (w << 4) + (g << 2) + r;
      int d = (f << 4) + li;
      atomicAdd(&out[((size_t)(b * NN + i)) * FOUTE + (hh << 6) + d], acc[f][r]);
    }
}

extern "C" void kernel_launch(void* const* d_in, const int* in_sizes, int n_in,
                              void* d_out, int out_size, void* d_ws, size_t ws_size,
                              hipStream_t stream) {
  const float* hIn  = (const float*)d_in[0];
  const int*   adj  = (const int*)d_in[1];
  const float* W    = (const float*)d_in[2];
  const float* attn = (const float*)d_in[3];
  float* out = (float*)d_out;
  float* outMean = out + (size_t)BB * NN * FOUTE;

  // workspace: hpT bf16 | s | t | c | t4 | packed adj bits  (~7 MB)
  ushort_t* hpT = (ushort_t*)d_ws;                        // 16*64*2048 ushorts = 4 MB
  float* sB  = (float*)(hpT + (size_t)BB * HH * DD * NN); // 32768 each
  float* tB  = sB + BB * HH * NN;
  float* cB  = tB + BB * HH * NN;
  float* tB4 = cB + BB * HH * NN;                         // 32768 (packed [b][n][h])
  u64* pack  = (u64*)(tB4 + BB * HH * NN);                // 2 MB

  // fused: x<128 -> projection GEMM tile (y = head); x>=128 -> pack row ((x-128)<<2)|y (+ zero h_new)
  hipLaunchKernelGGL(k_pg,  dim3(128 + 2048, HH), dim3(256), 0, stream,
                     hIn, W, attn, hpT, sB, tB, tB4, adj, pack, (float4*)out);
  hipLaunchKernelGGL(k_mls, dim3((BB * NN) / 8), dim3(256), 0, stream, sB, tB4, pack, cB, outMean);
  hipLaunchKernelGGL(k_pv,  dim3(BB * HH * (NN / 64), 2), dim3(256), 0, stream, hpT, sB, cB, tB, pack, out);
}

// Round 23
// 94.421 us; speedup vs baseline: 1.3027x; 1.3027x over previous
//
#include <hip/hip_runtime.h>
#include <math.h>

typedef unsigned long long u64;
typedef unsigned short ushort_t;
typedef float f32x4 __attribute__((ext_vector_type(4)));
typedef short short8 __attribute__((ext_vector_type(8)));

#define BB 4
#define NN 2048
#define FINE 256
#define FOUTE 256
#define HH 4
#define DD 64
#define NW 32   // 2048/64 packed words per adj row
#define L2E 1.44269504088896340736f

#define EXP2F(x) __builtin_amdgcn_exp2f(x)   // v_exp_f32: 2^x
#define LOG2F(x) __builtin_amdgcn_logf(x)    // v_log_f32: log2(x)

__device__ __forceinline__ float lrelu(float x) { return fmaxf(x, 0.2f * x); }

__device__ __forceinline__ unsigned short f2bf(float x) {   // fp32 -> bf16 RNE
  unsigned u = __float_as_uint(x);
  unsigned r = u + 0x7FFFu + ((u >> 16) & 1u);
  return (unsigned short)(r >> 16);
}

__device__ __forceinline__ unsigned cvtpk(float lo, float hi) {  // 2xf32 -> packed bf16 pair, 1 op
  unsigned r;
  asm("v_cvt_pk_bf16_f32 %0, %1, %2" : "=v"(r) : "v"(lo), "v"(hi));
  return r;
}

// ---------------- K0: pack adj -> bitmask; first 2048 blocks also zero h_new (0 LDS, full occupancy) ----------------
__global__ __launch_bounds__(256) void k_pack(const int* __restrict__ adj, u64* __restrict__ pack,
                                              float4* __restrict__ outZero) {
  int row = blockIdx.x;                 // b*N + i
  if (row < 2048) outZero[(size_t)row * 256 + threadIdx.x] = make_float4(0.f, 0.f, 0.f, 0.f);
  int wv = threadIdx.x >> 6, ln = threadIdx.x & 63;
  const int* arow = adj + (size_t)row * NN;
  u64* prow = pack + (size_t)row * NW;
  for (int w = wv; w < NW; w += 4) {
    u64 m = __ballot(arow[(w << 6) + ln] != 0);
    if (ln == 0) prow[w] = m;
  }
}

// ---------------- K1: projection GEMM via bf16 MFMA + fused s/t (log2 domain) + transposed bf16 hp ----------------
__global__ __launch_bounds__(256) void k_gemm1(const float* __restrict__ hI, const float* __restrict__ W,
                                               const float* __restrict__ attn,
                                               ushort_t* __restrict__ hpT,
                                               float* __restrict__ sB, float* __restrict__ tB,
                                               float* __restrict__ tB4) {
  __shared__ ushort_t Ab[64 * 256];     // [m][k] bf16, byte ^= (m&7)<<4 within row
  __shared__ ushort_t Bb[64 * 256];     // [d][k] bf16, same swizzle
  __shared__ ushort_t tT[64][72];       // transposed bf16 tile [d][token]
  int m0 = blockIdx.x * 64;             // over M = B*N
  int hh = blockIdx.y;
  int f0 = hh * 64;
  int tid = threadIdx.x;
  int w = tid >> 6, lane = tid & 63;
  int li = lane & 15, g = lane >> 4;

#pragma unroll
  for (int q = 0; q < 16; ++q) {
    int fi = (q << 8) + tid;            // 0..4095 float4-chunks
    int row = fi >> 6, f4 = fi & 63;
    float4 va = *(const float4*)&hI[(size_t)(m0 + row) * FINE + (f4 << 2)];
    float4 vb = *(const float4*)&W[(size_t)(f0 + row) * FINE + (f4 << 2)];
    int byteOff = (row << 9) + ((f4 << 3) ^ ((row & 7) << 4));
    *(uint2*)((char*)Ab + byteOff) = make_uint2(cvtpk(va.x, va.y), cvtpk(va.z, va.w));
    *(uint2*)((char*)Bb + byteOff) = make_uint2(cvtpk(vb.x, vb.y), cvtpk(vb.z, vb.w));
  }
  __syncthreads();

  f32x4 acc[4] = {};
  int arow = (w << 4) + li;
  int abase = arow << 9, asw = (arow & 7) << 4;
#pragma unroll
  for (int kk = 0; kk < 8; ++kk) {
    short8 a = *(const short8*)((char*)Ab + abase + (((kk << 6) + (g << 4)) ^ asw));
#pragma unroll
    for (int f = 0; f < 4; ++f) {
      int brow = (f << 4) + li;
      short8 b = *(const short8*)((char*)Bb + (brow << 9) + (((kk << 6) + (g << 4)) ^ ((brow & 7) << 4)));
      acc[f] = __builtin_amdgcn_mfma_f32_16x16x32_bf16(a, b, acc[f], 0, 0, 0);
    }
  }

  // ---- fused s/t from acc, scaled by log2(e): downstream softmax runs in exp2/log2 domain ----
  float as4[4], ad4[4];
#pragma unroll
  for (int f = 0; f < 4; ++f) {
    as4[f] = attn[(hh << 7) + (f << 4) + li] * L2E;
    ad4[f] = attn[(hh << 7) + 64 + (f << 4) + li] * L2E;
  }
  float ps[4] = {0.f, 0.f, 0.f, 0.f}, pt[4] = {0.f, 0.f, 0.f, 0.f};
#pragma unroll
  for (int f = 0; f < 4; ++f)
#pragma unroll
    for (int r = 0; r < 4; ++r) { ps[r] += acc[f][r] * as4[f]; pt[r] += acc[f][r] * ad4[f]; }
#pragma unroll
  for (int off = 1; off <= 8; off <<= 1) {
#pragma unroll
    for (int r = 0; r < 4; ++r) { ps[r] += __shfl_xor(ps[r], off); pt[r] += __shfl_xor(pt[r], off); }
  }
  int b0 = m0 >> 11, n0 = m0 & (NN - 1);
  if (li == 0) {
#pragma unroll
    for (int r = 0; r < 4; ++r) {
      int nn = n0 + (w << 4) + (g << 2) + r;
      size_t idx = (size_t)(b0 * HH + hh) * NN + nn;
      sB[idx] = ps[r]; tB[idx] = pt[r];
      tB4[((size_t)b0 * NN + nn) * 4 + hh] = pt[r];
    }
  }
  // ---- transposed bf16 store via LDS ----
#pragma unroll
  for (int f = 0; f < 4; ++f)
#pragma unroll
    for (int r = 0; r < 4; ++r)
      tT[(f << 4) + li][(w << 4) + (g << 2) + r] = f2bf(acc[f][r]);
  __syncthreads();
#pragma unroll
  for (int q = 0; q < 2; ++q) {
    int dr = (q << 5) + (tid >> 3);
    int seg = tid & 7;
    *(short8*)&hpT[((size_t)((b0 * HH + hh) << 6) + dr) * NN + n0 + (seg << 3)] =
        *(const short8*)&tT[dr][seg << 3];
  }
}

// ---------------- K2: fused ml+mean (log2 domain), LDS-staged t4, 8 rows/block, 1024 blocks ----------------
__global__ __launch_bounds__(256) void k_mls(const float* __restrict__ sB, const float* __restrict__ tB4,
                                             const u64* __restrict__ pack, float* __restrict__ cB,
                                             float* __restrict__ outMean) {
  __shared__ float4 t4s[2048];          // 32 KB: whole t4 table of this b
  __shared__ float4 wpart[4];
  int tid = threadIdx.x;
  int lane = tid & 63;
  int wv = tid >> 6;
  int bbase = blockIdx.x << 3;          // 8 rows per block, never straddles b
  int b = bbase >> 11;
  const float4* t4 = (const float4*)tB4 + (size_t)b * NN;
#pragma unroll
  for (int q = 0; q < 8; ++q) t4s[(q << 8) + tid] = t4[(q << 8) + tid];
  __syncthreads();

  // ---- block-wide unmasked max of t per head (softmax shift-invariance) ----
  float4 pm = make_float4(-1e30f, -1e30f, -1e30f, -1e30f);
#pragma unroll
  for (int q = 0; q < 8; ++q) {
    float4 tv = t4s[(wv << 9) + (q << 6) + lane];
    pm.x = fmaxf(pm.x, tv.x); pm.y = fmaxf(pm.y, tv.y);
    pm.z = fmaxf(pm.z, tv.z); pm.w = fmaxf(pm.w, tv.w);
  }
#pragma unroll
  for (int off = 32; off; off >>= 1) {
    pm.x = fmaxf(pm.x, __shfl_xor(pm.x, off));
    pm.y = fmaxf(pm.y, __shfl_xor(pm.y, off));
    pm.z = fmaxf(pm.z, __shfl_xor(pm.z, off));
    pm.w = fmaxf(pm.w, __shfl_xor(pm.w, off));
  }
  if (lane == 0) wpart[wv] = pm;
  __syncthreads();
  float4 q0 = wpart[0], q1 = wpart[1], q2 = wpart[2], q3 = wpart[3];
  float tmax[4] = {fmaxf(fmaxf(q0.x, q1.x), fmaxf(q2.x, q3.x)),
                   fmaxf(fmaxf(q0.y, q1.y), fmaxf(q2.y, q3.y)),
                   fmaxf(fmaxf(q0.z, q1.z), fmaxf(q2.z, q3.z)),
                   fmaxf(fmaxf(q0.w, q1.w), fmaxf(q2.w, q3.w))};

  int r0 = __builtin_amdgcn_readfirstlane(bbase + (wv << 1));   // first of this wave's 2 rows
  const u64* p0 = pack + (size_t)(r0 + 0) * NW;
  const u64* p1 = pack + (size_t)(r0 + 1) * NW;
  float sv[2][4], Ah[2][4], Bh[2][4], mh[2][4];
#pragma unroll
  for (int r = 0; r < 2; ++r)
#pragma unroll
    for (int h = 0; h < 4; ++h) {
      float s = sB[(size_t)(b * HH + h) * NN + ((r0 + r) & (NN - 1))];
      float m = lrelu(s + tmax[h]);
      sv[r][h] = s; mh[r][h] = m; Ah[r][h] = s - m; Bh[r][h] = fmaf(0.2f, s, -m);
    }
  unsigned mr0 = 0, mr1 = 0;            // bit k = adj(row, 64k+lane)
  float4 ls0 = make_float4(0.f, 0.f, 0.f, 0.f), ls1 = ls0;
#pragma unroll 4
  for (int k = 0; k < NW; ++k) {
    bool b0 = (p0[k] >> lane) & 1ull, b1 = (p1[k] >> lane) & 1ull;
    mr0 |= (unsigned)b0 << k; mr1 |= (unsigned)b1 << k;
    float4 tv = t4s[(k << 6) + lane];
    ls0.x += b0 ? EXP2F(fmaxf(tv.x + Ah[0][0], fmaf(0.2f, tv.x, Bh[0][0]))) : 0.f;
    ls0.y += b0 ? EXP2F(fmaxf(tv.y + Ah[0][1], fmaf(0.2f, tv.y, Bh[0][1]))) : 0.f;
    ls0.z += b0 ? EXP2F(fmaxf(tv.z + Ah[0][2], fmaf(0.2f, tv.z, Bh[0][2]))) : 0.f;
    ls0.w += b0 ? EXP2F(fmaxf(tv.w + Ah[0][3], fmaf(0.2f, tv.w, Bh[0][3]))) : 0.f;
    ls1.x += b1 ? EXP2F(fmaxf(tv.x + Ah[1][0], fmaf(0.2f, tv.x, Bh[1][0]))) : 0.f;
    ls1.y += b1 ? EXP2F(fmaxf(tv.y + Ah[1][1], fmaf(0.2f, tv.y, Bh[1][1]))) : 0.f;
    ls1.z += b1 ? EXP2F(fmaxf(tv.z + Ah[1][2], fmaf(0.2f, tv.z, Bh[1][2]))) : 0.f;
    ls1.w += b1 ? EXP2F(fmaxf(tv.w + Ah[1][3], fmaf(0.2f, tv.w, Bh[1][3]))) : 0.f;
  }
#pragma unroll
  for (int off = 32; off; off >>= 1) {
    ls0.x += __shfl_xor(ls0.x, off); ls0.y += __shfl_xor(ls0.y, off);
    ls0.z += __shfl_xor(ls0.z, off); ls0.w += __shfl_xor(ls0.w, off);
    ls1.x += __shfl_xor(ls1.x, off); ls1.y += __shfl_xor(ls1.y, off);
    ls1.z += __shfl_xor(ls1.z, off); ls1.w += __shfl_xor(ls1.w, off);
  }
  float A2[2][4], B2[2][4];
  float lv0[4] = {ls0.x, ls0.y, ls0.z, ls0.w};
  float lv1[4] = {ls1.x, ls1.y, ls1.z, ls1.w};
#pragma unroll
  for (int h = 0; h < 4; ++h) {
    float c0 = mh[0][h] + LOG2F(lv0[h]);
    float c1 = mh[1][h] + LOG2F(lv1[h]);
    A2[0][h] = sv[0][h] - c0; B2[0][h] = fmaf(0.2f, sv[0][h], -c0);
    A2[1][h] = sv[1][h] - c1; B2[1][h] = fmaf(0.2f, sv[1][h], -c1);
    if (lane == 0) {
      cB[(size_t)(b * HH + h) * NN + ((r0 + 0) & (NN - 1))] = c0;
      cB[(size_t)(b * HH + h) * NN + ((r0 + 1) & (NN - 1))] = c1;
    }
  }
#pragma unroll 2
  for (int k = 0; k < NW; ++k) {
    float4 tv = t4s[(k << 6) + lane];
    float tvv[4] = {tv.x, tv.y, tv.z, tv.w};
    float a0 = 0.f, a1 = 0.f;
#pragma unroll
    for (int h = 0; h < 4; ++h) {
      a0 += EXP2F(fmaxf(tvv[h] + A2[0][h], fmaf(0.2f, tvv[h], B2[0][h])));
      a1 += EXP2F(fmaxf(tvv[h] + A2[1][h], fmaf(0.2f, tvv[h], B2[1][h])));
    }
    outMean[(size_t)(r0 + 0) * NN + (k << 6) + lane] = ((mr0 >> k) & 1u) ? 0.25f * a0 : 0.0f;
    outMean[(size_t)(r0 + 1) * NN + (k << 6) + lane] = ((mr1 >> k) & 1u) ? 0.25f * a1 : 0.0f;
  }
}

// ---------------- K3: h_new = alpha @ hp via bf16 MFMA; distance-2 pipeline, j-half split;
// block's 4 KB t-half staged ONCE in LDS (r22-verified) ----------------
__global__ __launch_bounds__(256) void k_pv(const ushort_t* __restrict__ hpT,
                                            const float* __restrict__ sB, const float* __restrict__ cB,
                                            const float* __restrict__ tB, const u64* __restrict__ pack,
                                            float* __restrict__ out) {
  __shared__ ushort_t hpTile[2][4096];  // [buf][64 d-rows][64 j] bf16, XOR-swizzled (slot ^= drow&7)
  __shared__ float4 tLds[256];          // 4 KB: this block's j-half of t
  int blk = blockIdx.x;
  int jh = blockIdx.y;                  // j-half: jc in [16*jh, 16*jh+16)
  int it = blk & 31, bh = blk >> 5;
  int b = bh >> 2, hh = bh & 3;
  int i0 = it << 6;
  int tid = threadIdx.x;
  int w = tid >> 6, lane = tid & 63;
  int li = lane & 15, g = lane >> 4;
  int irow = i0 + (w << 4) + li;        // alpha row this lane generates
  float sI = sB[(size_t)bh * NN + irow];
  float cI = cB[(size_t)bh * NN + irow];
  float A0 = sI - cI, B0 = fmaf(0.2f, sI, -cI);   // exact: max(x,0.2x)-c == max(x-c, 0.2x-c)
  const u64* packRow = pack + ((size_t)b * NN + irow) * NW;
  const float* tRow = tB + (size_t)bh * NN;

  int drow0 = (w << 4) + (lane >> 3);           // q=0 rows; q=1 adds 8
  int xslot = (lane & 7) ^ (lane >> 3);         // (slot ^ drow&7); same for q=0/1
  const ushort_t* srcBase0 = hpT + ((size_t)(bh << 6) + drow0) * NN + (xslot << 3);
  const ushort_t* srcBase1 = srcBase0 + (size_t)8 * NN;

#define STAGE(buf, j0c)                                                                        \
  do {                                                                                         \
    __builtin_amdgcn_global_load_lds(                                                          \
        (const __attribute__((address_space(1))) void*)(srcBase0 + (j0c)),                     \
        (__attribute__((address_space(3))) void*)&hpTile[buf][(w << 10)], 16, 0, 0);           \
    __builtin_amdgcn_global_load_lds(                                                          \
        (const __attribute__((address_space(1))) void*)(srcBase1 + (j0c)),                     \
        (__attribute__((address_space(3))) void*)&hpTile[buf][(w << 10) + 512], 16, 0, 0);     \
  } while (0)

  f32x4 acc[4] = {};
  int jc0 = jh << 4;
  STAGE(0, jc0 << 6);
  STAGE(1, (jc0 + 1) << 6);
  tLds[tid] = ((const float4*)(tRow + (jc0 << 6)))[tid];
  u64 wbits = packRow[jc0];             // vector load AFTER STAGEs: its vmcnt drain covers them
  __syncthreads();                      // tLds ready
  int cur = 0;

  for (int jc = jc0; jc < jc0 + 16; ++jc) {
    const float4* tq = tLds + ((jc - jc0) << 4) + (g << 1);
    float4 ta0 = tq[0], ta1 = tq[1], tb0 = tq[8], tb1 = tq[9];   // +32 floats = +8 float4
    float tva[8] = {ta0.x, ta0.y, ta0.z, ta0.w, ta1.x, ta1.y, ta1.z, ta1.w};
    float tvb[8] = {tb0.x, tb0.y, tb0.z, tb0.w, tb1.x, tb1.y, tb1.z, tb1.w};
    unsigned bits0 = (unsigned)(wbits >> (g << 3));
    unsigned bits1 = (unsigned)(wbits >> (32 + (g << 3)));
    float ea[8], eb[8];
#pragma unroll
    for (int jj = 0; jj < 8; ++jj) {
      float e0 = EXP2F(fmaxf(tva[jj] + A0, fmaf(0.2f, tva[jj], B0)));
      ea[jj] = ((bits0 >> jj) & 1u) ? e0 : 0.0f;
      float e1 = EXP2F(fmaxf(tvb[jj] + A0, fmaf(0.2f, tvb[jj], B0)));
      eb[jj] = ((bits1 >> jj) & 1u) ? e1 : 0.0f;
    }
    uint4 ua, ub;
    ua.x = cvtpk(ea[0], ea[1]); ua.y = cvtpk(ea[2], ea[3]);
    ua.z = cvtpk(ea[4], ea[5]); ua.w = cvtpk(ea[6], ea[7]);
    ub.x = cvtpk(eb[0], eb[1]); ub.y = cvtpk(eb[2], eb[3]);
    ub.z = cvtpk(eb[4], eb[5]); ub.w = cvtpk(eb[6], eb[7]);
    short8 a0 = __builtin_bit_cast(short8, ua);
    short8 a1 = __builtin_bit_cast(short8, ub);

    if (jc < jc0 + 15) wbits = packRow[jc + 1];   // preload mask for jc+1 under MFMA phase

    asm volatile("" ::: "memory");
    __builtin_amdgcn_sched_barrier(0);
    __builtin_amdgcn_s_barrier();
    __builtin_amdgcn_sched_barrier(0);

    const char* tile = (const char*)hpTile[cur];
#pragma unroll
    for (int f = 0; f < 4; ++f) {
      int dr = (f << 4) + li;
      int ro = dr << 7;
      int sw = (dr & 7) << 4;
      short8 b0 = *(const short8*)(tile + ro + ((g << 4) ^ sw));
      short8 b1 = *(const short8*)(tile + ro + ((64 + (g << 4)) ^ sw));
      acc[f] = __builtin_amdgcn_mfma_f32_16x16x32_bf16(a0, b0, acc[f], 0, 0, 0);
      acc[f] = __builtin_amdgcn_mfma_f32_16x16x32_bf16(a1, b1, acc[f], 0, 0, 0);
    }

    asm volatile("s_waitcnt lgkmcnt(0)" ::: "memory");
    __builtin_amdgcn_sched_barrier(0);
    __builtin_amdgcn_s_barrier();

    if (jc + 2 < jc0 + 16) STAGE(cur, (jc + 2) << 6);
    cur ^= 1;
  }
#undef STAGE

#pragma unroll
  for (int f = 0; f < 4; ++f)
#pragma unroll
    for (int r = 0; r < 4; ++r) {
      int i = i0 + (w << 4) + (g << 2) + r;
      int d = (f << 4) + li;
      atomicAdd(&out[((size_t)(b * NN + i)) * FOUTE + (hh << 6) + d], acc[f][r]);
    }
}

extern "C" void kernel_launch(void* const* d_in, const int* in_sizes, int n_in,
                              void* d_out, int out_size, void* d_ws, size_t ws_size,
                              hipStream_t stream) {
  const float* hIn  = (const float*)d_in[0];
  const int*   adj  = (const int*)d_in[1];
  const float* W    = (const float*)d_in[2];
  const float* attn = (const float*)d_in[3];
  float* out = (float*)d_out;
  float* outMean = out + (size_t)BB * NN * FOUTE;

  // workspace: hpT bf16 | s | t | c | t4 | packed adj bits  (~7 MB)
  ushort_t* hpT = (ushort_t*)d_ws;                        // 16*64*2048 ushorts = 4 MB
  float* sB  = (float*)(hpT + (size_t)BB * HH * DD * NN); // 32768 each
  float* tB  = sB + BB * HH * NN;
  float* cB  = tB + BB * HH * NN;
  float* tB4 = cB + BB * HH * NN;                         // 32768 (packed [b][n][h])
  u64* pack  = (u64*)(tB4 + BB * HH * NN);                // 2 MB

  hipLaunchKernelGGL(k_pack,  dim3(BB * NN), dim3(256), 0, stream, adj, pack, (float4*)out);
  hipLaunchKernelGGL(k_gemm1, dim3((BB * NN) / 64, HH), dim3(256), 0, stream, hIn, W, attn, hpT, sB, tB, tB4);
  hipLaunchKernelGGL(k_mls,   dim3((BB * NN) / 8), dim3(256), 0, stream, sB, tB4, pack, cB, outMean);
  hipLaunchKernelGGL(k_pv,    dim3(BB * HH * (NN / 64), 2), dim3(256), 0, stream, hpT, sB, cB, tB, pack, out);
}

// Round 24
// 93.446 us; speedup vs baseline: 1.3163x; 1.0104x over previous
//
#include <hip/hip_runtime.h>
#include <math.h>

typedef unsigned long long u64;
typedef unsigned short ushort_t;
typedef float f32x4 __attribute__((ext_vector_type(4)));
typedef short short8 __attribute__((ext_vector_type(8)));

#define BB 4
#define NN 2048
#define FINE 256
#define FOUTE 256
#define HH 4
#define DD 64
#define NW 32   // 2048/64 packed words per adj row
#define L2E 1.44269504088896340736f

#define EXP2F(x) __builtin_amdgcn_exp2f(x)   // v_exp_f32: 2^x
#define LOG2F(x) __builtin_amdgcn_logf(x)    // v_log_f32: log2(x)

__device__ __forceinline__ float lrelu(float x) { return fmaxf(x, 0.2f * x); }

__device__ __forceinline__ unsigned short f2bf(float x) {   // fp32 -> bf16 RNE
  unsigned u = __float_as_uint(x);
  unsigned r = u + 0x7FFFu + ((u >> 16) & 1u);
  return (unsigned short)(r >> 16);
}

__device__ __forceinline__ unsigned cvtpk(float lo, float hi) {  // 2xf32 -> packed bf16 pair, 1 op
  unsigned r;
  asm("v_cvt_pk_bf16_f32 %0, %1, %2" : "=v"(r) : "v"(lo), "v"(hi));
  return r;
}

// ---------------- K0: pack adj -> bitmask; first 2048 blocks also zero h_new (0 LDS, full occupancy) ----------------
__global__ __launch_bounds__(256) void k_pack(const int* __restrict__ adj, u64* __restrict__ pack,
                                              float4* __restrict__ outZero) {
  int row = blockIdx.x;                 // b*N + i
  if (row < 2048) outZero[(size_t)row * 256 + threadIdx.x] = make_float4(0.f, 0.f, 0.f, 0.f);
  int wv = threadIdx.x >> 6, ln = threadIdx.x & 63;
  const int* arow = adj + (size_t)row * NN;
  u64* prow = pack + (size_t)row * NW;
  for (int w = wv; w < NW; w += 4) {
    u64 m = __ballot(arow[(w << 6) + ln] != 0);
    if (ln == 0) prow[w] = m;
  }
}

// ---------------- K1: projection GEMM via bf16 MFMA + fused s/t (log2 domain) + transposed bf16 hp ----------------
__global__ __launch_bounds__(256) void k_gemm1(const float* __restrict__ hI, const float* __restrict__ W,
                                               const float* __restrict__ attn,
                                               ushort_t* __restrict__ hpT,
                                               float* __restrict__ sB, float* __restrict__ tB,
                                               float* __restrict__ tB4) {
  __shared__ ushort_t Ab[64 * 256];     // [m][k] bf16, byte ^= (m&7)<<4 within row
  __shared__ ushort_t Bb[64 * 256];     // [d][k] bf16, same swizzle
  __shared__ ushort_t tT[64][72];       // transposed bf16 tile [d][token]
  int m0 = blockIdx.x * 64;             // over M = B*N
  int hh = blockIdx.y;
  int f0 = hh * 64;
  int tid = threadIdx.x;
  int w = tid >> 6, lane = tid & 63;
  int li = lane & 15, g = lane >> 4;

#pragma unroll
  for (int q = 0; q < 16; ++q) {
    int fi = (q << 8) + tid;            // 0..4095 float4-chunks
    int row = fi >> 6, f4 = fi & 63;
    float4 va = *(const float4*)&hI[(size_t)(m0 + row) * FINE + (f4 << 2)];
    float4 vb = *(const float4*)&W[(size_t)(f0 + row) * FINE + (f4 << 2)];
    int byteOff = (row << 9) + ((f4 << 3) ^ ((row & 7) << 4));
    *(uint2*)((char*)Ab + byteOff) = make_uint2(cvtpk(va.x, va.y), cvtpk(va.z, va.w));
    *(uint2*)((char*)Bb + byteOff) = make_uint2(cvtpk(vb.x, vb.y), cvtpk(vb.z, vb.w));
  }
  __syncthreads();

  f32x4 acc[4] = {};
  int arow = (w << 4) + li;
  int abase = arow << 9, asw = (arow & 7) << 4;
#pragma unroll
  for (int kk = 0; kk < 8; ++kk) {
    short8 a = *(const short8*)((char*)Ab + abase + (((kk << 6) + (g << 4)) ^ asw));
#pragma unroll
    for (int f = 0; f < 4; ++f) {
      int brow = (f << 4) + li;
      short8 b = *(const short8*)((char*)Bb + (brow << 9) + (((kk << 6) + (g << 4)) ^ ((brow & 7) << 4)));
      acc[f] = __builtin_amdgcn_mfma_f32_16x16x32_bf16(a, b, acc[f], 0, 0, 0);
    }
  }

  // ---- fused s/t from acc, scaled by log2(e): downstream softmax runs in exp2/log2 domain ----
  float as4[4], ad4[4];
#pragma unroll
  for (int f = 0; f < 4; ++f) {
    as4[f] = attn[(hh << 7) + (f << 4) + li] * L2E;
    ad4[f] = attn[(hh << 7) + 64 + (f << 4) + li] * L2E;
  }
  float ps[4] = {0.f, 0.f, 0.f, 0.f}, pt[4] = {0.f, 0.f, 0.f, 0.f};
#pragma unroll
  for (int f = 0; f < 4; ++f)
#pragma unroll
    for (int r = 0; r < 4; ++r) { ps[r] += acc[f][r] * as4[f]; pt[r] += acc[f][r] * ad4[f]; }
#pragma unroll
  for (int off = 1; off <= 8; off <<= 1) {
#pragma unroll
    for (int r = 0; r < 4; ++r) { ps[r] += __shfl_xor(ps[r], off); pt[r] += __shfl_xor(pt[r], off); }
  }
  int b0 = m0 >> 11, n0 = m0 & (NN - 1);
  if (li == 0) {
#pragma unroll
    for (int r = 0; r < 4; ++r) {
      int nn = n0 + (w << 4) + (g << 2) + r;
      size_t idx = (size_t)(b0 * HH + hh) * NN + nn;
      sB[idx] = ps[r]; tB[idx] = pt[r];
      tB4[((size_t)b0 * NN + nn) * 4 + hh] = pt[r];
    }
  }
  // ---- transposed bf16 store via LDS ----
#pragma unroll
  for (int f = 0; f < 4; ++f)
#pragma unroll
    for (int r = 0; r < 4; ++r)
      tT[(f << 4) + li][(w << 4) + (g << 2) + r] = f2bf(acc[f][r]);
  __syncthreads();
#pragma unroll
  for (int q = 0; q < 2; ++q) {
    int dr = (q << 5) + (tid >> 3);
    int seg = tid & 7;
    *(short8*)&hpT[((size_t)((b0 * HH + hh) << 6) + dr) * NN + n0 + (seg << 3)] =
        *(const short8*)&tT[dr][seg << 3];
  }
}

// ---------------- K2: fused ml+mean (log2 domain), LDS-staged t4, 8 rows/block, 1024 blocks ----------------
__global__ __launch_bounds__(256) void k_mls(const float* __restrict__ sB, const float* __restrict__ tB4,
                                             const u64* __restrict__ pack, float* __restrict__ cB,
                                             float* __restrict__ outMean) {
  __shared__ float4 t4s[2048];          // 32 KB: whole t4 table of this b
  __shared__ float4 wpart[4];
  int tid = threadIdx.x;
  int lane = tid & 63;
  int wv = tid >> 6;
  int bbase = blockIdx.x << 3;          // 8 rows per block, never straddles b
  int b = bbase >> 11;
  const float4* t4 = (const float4*)tB4 + (size_t)b * NN;
#pragma unroll
  for (int q = 0; q < 8; ++q) t4s[(q << 8) + tid] = t4[(q << 8) + tid];
  __syncthreads();

  // ---- block-wide unmasked max of t per head (softmax shift-invariance) ----
  float4 pm = make_float4(-1e30f, -1e30f, -1e30f, -1e30f);
#pragma unroll
  for (int q = 0; q < 8; ++q) {
    float4 tv = t4s[(wv << 9) + (q << 6) + lane];
    pm.x = fmaxf(pm.x, tv.x); pm.y = fmaxf(pm.y, tv.y);
    pm.z = fmaxf(pm.z, tv.z); pm.w = fmaxf(pm.w, tv.w);
  }
#pragma unroll
  for (int off = 32; off; off >>= 1) {
    pm.x = fmaxf(pm.x, __shfl_xor(pm.x, off));
    pm.y = fmaxf(pm.y, __shfl_xor(pm.y, off));
    pm.z = fmaxf(pm.z, __shfl_xor(pm.z, off));
    pm.w = fmaxf(pm.w, __shfl_xor(pm.w, off));
  }
  if (lane == 0) wpart[wv] = pm;
  __syncthreads();
  float4 q0 = wpart[0], q1 = wpart[1], q2 = wpart[2], q3 = wpart[3];
  float tmax[4] = {fmaxf(fmaxf(q0.x, q1.x), fmaxf(q2.x, q3.x)),
                   fmaxf(fmaxf(q0.y, q1.y), fmaxf(q2.y, q3.y)),
                   fmaxf(fmaxf(q0.z, q1.z), fmaxf(q2.z, q3.z)),
                   fmaxf(fmaxf(q0.w, q1.w), fmaxf(q2.w, q3.w))};

  int r0 = __builtin_amdgcn_readfirstlane(bbase + (wv << 1));   // first of this wave's 2 rows
  const u64* p0 = pack + (size_t)(r0 + 0) * NW;
  const u64* p1 = pack + (size_t)(r0 + 1) * NW;
  float sv[2][4], Ah[2][4], Bh[2][4], mh[2][4];
#pragma unroll
  for (int r = 0; r < 2; ++r)
#pragma unroll
    for (int h = 0; h < 4; ++h) {
      float s = sB[(size_t)(b * HH + h) * NN + ((r0 + r) & (NN - 1))];
      float m = lrelu(s + tmax[h]);
      sv[r][h] = s; mh[r][h] = m; Ah[r][h] = s - m; Bh[r][h] = fmaf(0.2f, s, -m);
    }
  unsigned mr0 = 0, mr1 = 0;            // bit k = adj(row, 64k+lane)
  float4 ls0 = make_float4(0.f, 0.f, 0.f, 0.f), ls1 = ls0;
#pragma unroll 4
  for (int k = 0; k < NW; ++k) {
    bool b0 = (p0[k] >> lane) & 1ull, b1 = (p1[k] >> lane) & 1ull;
    mr0 |= (unsigned)b0 << k; mr1 |= (unsigned)b1 << k;
    float4 tv = t4s[(k << 6) + lane];
    ls0.x += b0 ? EXP2F(fmaxf(tv.x + Ah[0][0], fmaf(0.2f, tv.x, Bh[0][0]))) : 0.f;
    ls0.y += b0 ? EXP2F(fmaxf(tv.y + Ah[0][1], fmaf(0.2f, tv.y, Bh[0][1]))) : 0.f;
    ls0.z += b0 ? EXP2F(fmaxf(tv.z + Ah[0][2], fmaf(0.2f, tv.z, Bh[0][2]))) : 0.f;
    ls0.w += b0 ? EXP2F(fmaxf(tv.w + Ah[0][3], fmaf(0.2f, tv.w, Bh[0][3]))) : 0.f;
    ls1.x += b1 ? EXP2F(fmaxf(tv.x + Ah[1][0], fmaf(0.2f, tv.x, Bh[1][0]))) : 0.f;
    ls1.y += b1 ? EXP2F(fmaxf(tv.y + Ah[1][1], fmaf(0.2f, tv.y, Bh[1][1]))) : 0.f;
    ls1.z += b1 ? EXP2F(fmaxf(tv.z + Ah[1][2], fmaf(0.2f, tv.z, Bh[1][2]))) : 0.f;
    ls1.w += b1 ? EXP2F(fmaxf(tv.w + Ah[1][3], fmaf(0.2f, tv.w, Bh[1][3]))) : 0.f;
  }
#pragma unroll
  for (int off = 32; off; off >>= 1) {
    ls0.x += __shfl_xor(ls0.x, off); ls0.y += __shfl_xor(ls0.y, off);
    ls0.z += __shfl_xor(ls0.z, off); ls0.w += __shfl_xor(ls0.w, off);
    ls1.x += __shfl_xor(ls1.x, off); ls1.y += __shfl_xor(ls1.y, off);
    ls1.z += __shfl_xor(ls1.z, off); ls1.w += __shfl_xor(ls1.w, off);
  }
  float A2[2][4], B2[2][4];
  float lv0[4] = {ls0.x, ls0.y, ls0.z, ls0.w};
  float lv1[4] = {ls1.x, ls1.y, ls1.z, ls1.w};
#pragma unroll
  for (int h = 0; h < 4; ++h) {
    float c0 = mh[0][h] + LOG2F(lv0[h]);
    float c1 = mh[1][h] + LOG2F(lv1[h]);
    A2[0][h] = sv[0][h] - c0; B2[0][h] = fmaf(0.2f, sv[0][h], -c0);
    A2[1][h] = sv[1][h] - c1; B2[1][h] = fmaf(0.2f, sv[1][h], -c1);
    if (lane == 0) {
      cB[(size_t)(b * HH + h) * NN + ((r0 + 0) & (NN - 1))] = c0;
      cB[(size_t)(b * HH + h) * NN + ((r0 + 1) & (NN - 1))] = c1;
    }
  }
#pragma unroll 2
  for (int k = 0; k < NW; ++k) {
    float4 tv = t4s[(k << 6) + lane];
    float tvv[4] = {tv.x, tv.y, tv.z, tv.w};
    float a0 = 0.f, a1 = 0.f;
#pragma unroll
    for (int h = 0; h < 4; ++h) {
      a0 += EXP2F(fmaxf(tvv[h] + A2[0][h], fmaf(0.2f, tvv[h], B2[0][h])));
      a1 += EXP2F(fmaxf(tvv[h] + A2[1][h], fmaf(0.2f, tvv[h], B2[1][h])));
    }
    outMean[(size_t)(r0 + 0) * NN + (k << 6) + lane] = ((mr0 >> k) & 1u) ? 0.25f * a0 : 0.0f;
    outMean[(size_t)(r0 + 1) * NN + (k << 6) + lane] = ((mr1 >> k) & 1u) ? 0.25f * a1 : 0.0f;
  }
}

// ---------------- K3: h_new = alpha @ hp via bf16 MFMA; 4-deep LDS ring, ONE barrier per jc.
// Stage distance 2, buffers mod 4 -> STAGE(jc+2) never collides with MFMA reads (max barrier
// skew 1 interval: reads from buf[jc&3]; writes to buf[(jc+2)&3]). DMA-complete guarantee:
// each wave's alpha-gen(jc) waits on wbits(jc), issued AFTER its STAGE(jc) in program order,
// so barrier(jc) implies all STAGE(jc) DMAs drained. ----------------
__global__ __launch_bounds__(256) void k_pv(const ushort_t* __restrict__ hpT,
                                            const float* __restrict__ sB, const float* __restrict__ cB,
                                            const float* __restrict__ tB, const u64* __restrict__ pack,
                                            float* __restrict__ out) {
  __shared__ ushort_t hpTile[4][4096];  // ring of 4 [64 d-rows][64 j] bf16 tiles, XOR-swizzled
  __shared__ float4 tLds[256];          // 4 KB: this block's j-half of t
  int blk = blockIdx.x;
  int jh = blockIdx.y;                  // j-half: jc in [16*jh, 16*jh+16)
  int it = blk & 31, bh = blk >> 5;
  int b = bh >> 2, hh = bh & 3;
  int i0 = it << 6;
  int tid = threadIdx.x;
  int w = tid >> 6, lane = tid & 63;
  int li = lane & 15, g = lane >> 4;
  int irow = i0 + (w << 4) + li;        // alpha row this lane generates
  float sI = sB[(size_t)bh * NN + irow];
  float cI = cB[(size_t)bh * NN + irow];
  float A0 = sI - cI, B0 = fmaf(0.2f, sI, -cI);   // exact: max(x,0.2x)-c == max(x-c, 0.2x-c)
  const u64* packRow = pack + ((size_t)b * NN + irow) * NW;
  const float* tRow = tB + (size_t)bh * NN;

  int drow0 = (w << 4) + (lane >> 3);           // q=0 rows; q=1 adds 8
  int xslot = (lane & 7) ^ (lane >> 3);         // (slot ^ drow&7); same for q=0/1
  const ushort_t* srcBase0 = hpT + ((size_t)(bh << 6) + drow0) * NN + (xslot << 3);
  const ushort_t* srcBase1 = srcBase0 + (size_t)8 * NN;

#define STAGE(buf, j0c)                                                                        \
  do {                                                                                         \
    __builtin_amdgcn_global_load_lds(                                                          \
        (const __attribute__((address_space(1))) void*)(srcBase0 + (j0c)),                     \
        (__attribute__((address_space(3))) void*)&hpTile[buf][(w << 10)], 16, 0, 0);           \
    __builtin_amdgcn_global_load_lds(                                                          \
        (const __attribute__((address_space(1))) void*)(srcBase1 + (j0c)),                     \
        (__attribute__((address_space(3))) void*)&hpTile[buf][(w << 10) + 512], 16, 0, 0);     \
  } while (0)

  f32x4 acc[4] = {};
  int jc0 = jh << 4;                    // 0 or 16 -> jc0 & 3 == 0
  STAGE(0, jc0 << 6);
  STAGE(1, (jc0 + 1) << 6);
  tLds[tid] = ((const float4*)(tRow + (jc0 << 6)))[tid];
  u64 wbits = packRow[jc0];
  __syncthreads();                      // tLds ready; prologue STAGEs drained

  for (int jc = jc0; jc < jc0 + 16; ++jc) {
    // ---- alpha A-fragments (t from LDS, mask from register) ----
    const float4* tq = tLds + ((jc - jc0) << 4) + (g << 1);
    float4 ta0 = tq[0], ta1 = tq[1], tb0 = tq[8], tb1 = tq[9];
    float tva[8] = {ta0.x, ta0.y, ta0.z, ta0.w, ta1.x, ta1.y, ta1.z, ta1.w};
    float tvb[8] = {tb0.x, tb0.y, tb0.z, tb0.w, tb1.x, tb1.y, tb1.z, tb1.w};
    unsigned bits0 = (unsigned)(wbits >> (g << 3));
    unsigned bits1 = (unsigned)(wbits >> (32 + (g << 3)));
    float ea[8], eb[8];
#pragma unroll
    for (int jj = 0; jj < 8; ++jj) {
      float e0 = EXP2F(fmaxf(tva[jj] + A0, fmaf(0.2f, tva[jj], B0)));
      ea[jj] = ((bits0 >> jj) & 1u) ? e0 : 0.0f;
      float e1 = EXP2F(fmaxf(tvb[jj] + A0, fmaf(0.2f, tvb[jj], B0)));
      eb[jj] = ((bits1 >> jj) & 1u) ? e1 : 0.0f;
    }
    uint4 ua, ub;
    ua.x = cvtpk(ea[0], ea[1]); ua.y = cvtpk(ea[2], ea[3]);
    ua.z = cvtpk(ea[4], ea[5]); ua.w = cvtpk(ea[6], ea[7]);
    ub.x = cvtpk(eb[0], eb[1]); ub.y = cvtpk(eb[2], eb[3]);
    ub.z = cvtpk(eb[4], eb[5]); ub.w = cvtpk(eb[6], eb[7]);
    short8 a0 = __builtin_bit_cast(short8, ua);
    short8 a1 = __builtin_bit_cast(short8, ub);

    // preload mask for jc+1 (issued after STAGE(jc+1)... ensures barrier(jc+1) drains it)
    if (jc < jc0 + 15) wbits = packRow[jc + 1];

    // ---- single barrier: buf[jc&3] staged (all waves drained via their wbits(jc) wait) ----
    asm volatile("" ::: "memory");
    __builtin_amdgcn_sched_barrier(0);
    __builtin_amdgcn_s_barrier();
    __builtin_amdgcn_sched_barrier(0);

    const char* tile = (const char*)hpTile[jc & 3];
#pragma unroll
    for (int f = 0; f < 4; ++f) {
      int dr = (f << 4) + li;
      int ro = dr << 7;
      int sw = (dr & 7) << 4;
      short8 b0 = *(const short8*)(tile + ro + ((g << 4) ^ sw));
      short8 b1 = *(const short8*)(tile + ro + ((64 + (g << 4)) ^ sw));
      acc[f] = __builtin_amdgcn_mfma_f32_16x16x32_bf16(a0, b0, acc[f], 0, 0, 0);
      acc[f] = __builtin_amdgcn_mfma_f32_16x16x32_bf16(a1, b1, acc[f], 0, 0, 0);
    }

    // stage distance-2 into ring slot (jc+2)&3 — disjoint from any in-flight reads
    if (jc + 2 < jc0 + 16) STAGE((jc + 2) & 3, (jc + 2) << 6);
  }
#undef STAGE

#pragma unroll
  for (int f = 0; f < 4; ++f)
#pragma unroll
    for (int r = 0; r < 4; ++r) {
      int i = i0 + (w << 4) + (g << 2) + r;
      int d = (f << 4) + li;
      atomicAdd(&out[((size_t)(b * NN + i)) * FOUTE + (hh << 6) + d], acc[f][r]);
    }
}

extern "C" void kernel_launch(void* const* d_in, const int* in_sizes, int n_in,
                              void* d_out, int out_size, void* d_ws, size_t ws_size,
                              hipStream_t stream) {
  const float* hIn  = (const float*)d_in[0];
  const int*   adj  = (const int*)d_in[1];
  const float* W    = (const float*)d_in[2];
  const float* attn = (const float*)d_in[3];
  float* out = (float*)d_out;
  float* outMean = out + (size_t)BB * NN * FOUTE;

  // workspace: hpT bf16 | s | t | c | t4 | packed adj bits  (~7 MB)
  ushort_t* hpT = (ushort_t*)d_ws;                        // 16*64*2048 ushorts = 4 MB
  float* sB  = (float*)(hpT + (size_t)BB * HH * DD * NN); // 32768 each
  float* tB  = sB + BB * HH * NN;
  float* cB  = tB + BB * HH * NN;
  float* tB4 = cB + BB * HH * NN;                         // 32768 (packed [b][n][h])
  u64* pack  = (u64*)(tB4 + BB * HH * NN);                // 2 MB

  hipLaunchKernelGGL(k_pack,  dim3(BB * NN), dim3(256), 0, stream, adj, pack, (float4*)out);
  hipLaunchKernelGGL(k_gemm1, dim3((BB * NN) / 64, HH), dim3(256), 0, stream, hIn, W, attn, hpT, sB, tB, tB4);
  hipLaunchKernelGGL(k_mls,   dim3((BB * NN) / 8), dim3(256), 0, stream, sB, tB4, pack, cB, outMean);
  hipLaunchKernelGGL(k_pv,    dim3(BB * HH * (NN / 64), 2), dim3(256), 0, stream, hpT, sB, cB, tB, pack, out);
}